// Round 8
// baseline (1290.609 us; speedup 1.0000x reference)
//
#include <hip/hip_runtime.h>
#include <hip/hip_fp16.h>
#include <math.h>

#define BN    8
#define NN    2048
#define NP1   2049
#define VSTR  2056   // padded a/b vector stride (floats), 16B-aligned rows
#define DD    256
#define NITER 20
#define NBLK  256    // persistent grid size

// ws layout (floats): a[BN*VSTR] | b[BN*VSTR] | sums[41*BN] | bar[8] (int) | Kh[BN*NN*NN] (half)

__global__ void init_kernel(float* __restrict__ bvec, int nb, float* __restrict__ sums,
                            int* __restrict__ bar) {
    int tid = blockIdx.x * blockDim.x + threadIdx.x;
    int stride = gridDim.x * blockDim.x;
    for (int i = tid; i < nb; i += stride) bvec[i] = 1.0f;            // v0 = 0 -> b = 1
    for (int i = tid; i < 41 * BN; i += stride) sums[i] = (i < BN) ? (float)NN : 0.0f;
    if (tid < 8) bar[tid] = 0;
}

// K = exp(F^T F / 16), diag = 0. F16 variant writes half K (stride NN) to Kh;
// fp32 variant writes into out's top-left NxN (stride NP1). Symmetric: tj>=ti only.
template <bool F16>
__global__ __launch_bounds__(256) void build_k_kernel(const float* __restrict__ F,
                                                      float* __restrict__ out,
                                                      __half* __restrict__ Kh) {
    int ti = blockIdx.x, tj = blockIdx.y, bb = blockIdx.z;
    if (tj < ti) return;
    __shared__ float As[32][64];
    __shared__ float Bs[32][64];
    int t  = threadIdx.x;
    int tx = t & 15, ty = t >> 4;
    float acc[4][4] = {};
    const float* Fb = F + (size_t)bb * DD * NN;
    int i0 = ti * 64, j0 = tj * 64;
    for (int k0 = 0; k0 < DD; k0 += 32) {
#pragma unroll
        for (int v = 0; v < 2; v++) {
            int f = t + 256 * v;
            int row = f >> 4, c4 = (f & 15) * 4;
            *(float4*)&As[row][c4] = *(const float4*)&Fb[(size_t)(k0 + row) * NN + i0 + c4];
            *(float4*)&Bs[row][c4] = *(const float4*)&Fb[(size_t)(k0 + row) * NN + j0 + c4];
        }
        __syncthreads();
#pragma unroll
        for (int k = 0; k < 32; k++) {
            float4 av = *(float4*)&As[k][ty * 4];
            float4 bv = *(float4*)&Bs[k][tx * 4];
            float ar[4] = {av.x, av.y, av.z, av.w};
            float br[4] = {bv.x, bv.y, bv.z, bv.w};
#pragma unroll
            for (int r = 0; r < 4; r++)
#pragma unroll
                for (int c = 0; c < 4; c++)
                    acc[r][c] = fmaf(ar[r], br[c], acc[r][c]);
        }
        __syncthreads();
    }
#pragma unroll
    for (int r = 0; r < 4; r++) {
        int i = i0 + ty * 4 + r;
#pragma unroll
        for (int c = 0; c < 4; c++) {
            int j = j0 + tx * 4 + c;
            float Kv = (i == j) ? 0.0f : __expf(acc[r][c] * 0.0625f);  // 1/sqrt(256)
            if constexpr (F16) {
                __half* Khb = Kh + (size_t)bb * NN * NN;
                __half h = __float2half_rn(Kv);
                Khb[(size_t)i * NN + j] = h;
                if (tj > ti) Khb[(size_t)j * NN + i] = h;
            } else {
                float* outb = out + (size_t)bb * NP1 * NP1;
                outb[(size_t)i * NP1 + j] = Kv;
                if (tj > ti) outb[(size_t)j * NP1 + i] = Kv;
            }
        }
    }
}

__device__ __forceinline__ float2 h2f2(int u) {
    return __half22float2(__builtin_bit_cast(__half2, u));
}

// Persistent Sinkhorn, K in 16 named int4 regs/thread (64 VGPR of fp16).
// R4-R7 failure: VGPR_Count pinned at 64 — the RA remats the (invariant-
// address) K loads to reach its 8-waves/EU occupancy target, re-reading K
// from L3 every pass. Fix: (a) amdgpu_waves_per_eu(4,4) caps occupancy at
// 4 waves/EU -> 128-VGPR budget, removing the incentive; (b) PIN4 pipes
// each loaded component through opaque empty asm -> non-rematerializable,
// values MUST stay live in VGPRs.
// 256 blocks x 1024 threads = 1 block/CU. Block b: batch=b>>5, rows
// [(b&31)*64,+64). Thread t: row t>>4, cols [(t&15)*128,+128).
__global__ __launch_bounds__(1024)
__attribute__((amdgpu_waves_per_eu(4, 4)))
void sink_persist(const __half* __restrict__ K,
                  float* __restrict__ avec,
                  float* __restrict__ bvec,
                  float* __restrict__ sums,
                  int* __restrict__ bar,
                  const float* __restrict__ alpha) {
    int blk   = blockIdx.x;
    int batch = blk >> 5;
    int rb    = blk & 31;
    int tid   = threadIdx.x;
    int seg   = tid & 15;
    int row   = rb * 64 + (tid >> 4);

    const int4* src = (const int4*)(K + (((size_t)batch * NN + row) * NN) + seg * 128);
    int4 kv0  = src[0],  kv1  = src[1],  kv2  = src[2],  kv3  = src[3];
    int4 kv4  = src[4],  kv5  = src[5],  kv6  = src[6],  kv7  = src[7];
    int4 kv8  = src[8],  kv9  = src[9],  kv10 = src[10], kv11 = src[11];
    int4 kv12 = src[12], kv13 = src[13], kv14 = src[14], kv15 = src[15];

#define PIN4(V) asm volatile("" : "+v"(V.x), "+v"(V.y), "+v"(V.z), "+v"(V.w))
    PIN4(kv0);  PIN4(kv1);  PIN4(kv2);  PIN4(kv3);
    PIN4(kv4);  PIN4(kv5);  PIN4(kv6);  PIN4(kv7);
    PIN4(kv8);  PIN4(kv9);  PIN4(kv10); PIN4(kv11);
    PIN4(kv12); PIN4(kv13); PIN4(kv14); PIN4(kv15);
#undef PIN4

    __shared__ float xs[16 * 132];   // +4 floats pad per 128-seg
    __shared__ float wsum[16];

    float* av = avec + (size_t)batch * VSTR;
    float* bv = bvec + (size_t)batch * VSTR;
    float E    = __expf(alpha[0]);
    float binA = 0.f, binB = 1.0f;
    float S_in = 2048.0f;            // sum of vector entering current pass
    int   ep   = 0;                  // barrier generation target (monotonic)
    const float4* xp4 = (const float4*)(xs + seg * 132);

#define DOT_Q(KV, Q, ACC)                                                       \
    {                                                                           \
        float4 xv = xp4[2 * (Q)];                                               \
        float4 xw = xp4[2 * (Q) + 1];                                           \
        float2 a0 = h2f2(KV.x), a1 = h2f2(KV.y);                                \
        float2 a2 = h2f2(KV.z), a3 = h2f2(KV.w);                                \
        ACC = fmaf(a0.x, xv.x, ACC); ACC = fmaf(a0.y, xv.y, ACC);               \
        ACC = fmaf(a1.x, xv.z, ACC); ACC = fmaf(a1.y, xv.w, ACC);               \
        ACC = fmaf(a2.x, xw.x, ACC); ACC = fmaf(a2.y, xw.y, ACC);               \
        ACC = fmaf(a3.x, xw.z, ACC); ACC = fmaf(a3.y, xw.w, ACC);               \
    }

#define SINK_PASS(XIN, XOUT, BIN_IN, BIN_OUT, P, LAST)                          \
    {                                                                           \
        {   /* stage XIN[0..2048) into LDS (coalesced float2) */                \
            float2 v = ((const float2*)(XIN))[tid];                             \
            int j = tid * 2;                                                    \
            float* d = xs + ((j >> 7) * 132 + (j & 127));                       \
            d[0] = v.x; d[1] = v.y;                                             \
        }                                                                       \
        __syncthreads();                                                        \
        float dot0 = 0.f, dot1 = 0.f;                                           \
        DOT_Q(kv0,  0,  dot0) DOT_Q(kv1,  1,  dot1)                             \
        DOT_Q(kv2,  2,  dot0) DOT_Q(kv3,  3,  dot1)                             \
        DOT_Q(kv4,  4,  dot0) DOT_Q(kv5,  5,  dot1)                             \
        DOT_Q(kv6,  6,  dot0) DOT_Q(kv7,  7,  dot1)                             \
        DOT_Q(kv8,  8,  dot0) DOT_Q(kv9,  9,  dot1)                             \
        DOT_Q(kv10, 10, dot0) DOT_Q(kv11, 11, dot1)                             \
        DOT_Q(kv12, 12, dot0) DOT_Q(kv13, 13, dot1)                             \
        DOT_Q(kv14, 14, dot0) DOT_Q(kv15, 15, dot1)                             \
        float dot = dot0 + dot1;                                                \
        dot += __shfl_xor(dot, 1);                                              \
        dot += __shfl_xor(dot, 2);                                              \
        dot += __shfl_xor(dot, 4);                                              \
        dot += __shfl_xor(dot, 8);                                              \
        float val = (1.0f / 4096.0f) / (dot + E * (BIN_IN));                    \
        BIN_OUT = 0.5f / (E * (S_in + (BIN_IN)));                               \
        float ys = val;                                                         \
        ys += __shfl_xor(ys, 16);                                               \
        ys += __shfl_xor(ys, 32);                                               \
        if ((tid & 15) == 0) (XOUT)[row] = val;                                 \
        if ((tid & 63) == 0) wsum[tid >> 6] = ys;                               \
        __syncthreads();   /* vmem drained to cache by compiler's waitcnt */    \
        if (!(LAST)) {                                                          \
            ep += NBLK;                                                         \
            if (tid == 0) {                                                     \
                float s = 0.f;                                                  \
                _Pragma("unroll")                                               \
                for (int w = 0; w < 16; w++) s += wsum[w];                      \
                atomicAdd(&sums[(P) * BN + batch], s);                          \
                __hip_atomic_fetch_add(bar, 1, __ATOMIC_RELEASE,                \
                                       __HIP_MEMORY_SCOPE_AGENT);               \
                while (__hip_atomic_load(bar, __ATOMIC_RELAXED,                 \
                                         __HIP_MEMORY_SCOPE_AGENT) < ep)        \
                    __builtin_amdgcn_s_sleep(1);                                \
                __builtin_amdgcn_fence(__ATOMIC_ACQUIRE, "agent");              \
            }                                                                   \
            __syncthreads();                                                    \
            S_in = sums[(P) * BN + batch];                                      \
        }                                                                       \
    }

    for (int it2 = 0; it2 < NITER; it2++) {
        int p = 2 * it2 + 1;
        SINK_PASS(bv, av, binB, binA, p, false);
        SINK_PASS(av, bv, binA, binB, p + 1, (it2 == NITER - 1));
    }
#undef SINK_PASS
#undef DOT_Q

    if (tid == 0) { av[NN] = binA; bv[NN] = binB; }
}

// fp32 fallback pass (K in d_out, stride NP1) for ws-too-small case.
__global__ __launch_bounds__(256) void sink_pass_f32(const float* __restrict__ K,
                                                     const float* __restrict__ xin,
                                                     float* __restrict__ xout,
                                                     const float* __restrict__ sum_in,
                                                     float* __restrict__ sum_out,
                                                     const float* __restrict__ alpha) {
    int bb = blockIdx.y;
    int i0 = blockIdx.x * 16;
    __shared__ float xsl[NN];
    __shared__ float rowa[16];
    const float* xinb = xin + (size_t)bb * VSTR;
    int t = threadIdx.x;
    for (int j = t; j < NN; j += 256) xsl[j] = xinb[j];
    __syncthreads();
    float E  = __expf(alpha[0]);
    float xN = xinb[NN];
    int wave = t >> 6, lane = t & 63;
    const float* Kb = K + (size_t)bb * NP1 * NP1;
    for (int r = wave; r < 16; r += 4) {
        int i = i0 + r;
        const float* rowp = Kb + (size_t)i * NP1;
        float acc = 0.f;
        for (int j = lane; j < NN; j += 64) acc = fmaf(rowp[j], xsl[j], acc);
#pragma unroll
        for (int off = 32; off >= 1; off >>= 1) acc += __shfl_xor(acc, off);
        if (lane == 0) {
            float v = (1.0f / 4096.0f) / (acc + E * xN);
            xout[(size_t)bb * VSTR + i] = v;
            rowa[r] = v;
        }
    }
    __syncthreads();
    if (t == 0) {
        float s = 0.f;
#pragma unroll
        for (int r = 0; r < 16; r++) s += rowa[r];
        atomicAdd(sum_out + bb, s);
        if (blockIdx.x == 0) xout[(size_t)bb * VSTR + NN] = 0.5f / (E * (sum_in[bb] + xN));
    }
}

// out[i,j] = K*a_i*b_j*4096*cost (i,j<N), bins use E. F16: K from Kh; else in-place.
template <bool F16>
__global__ __launch_bounds__(256) void final_kernel(float* __restrict__ out,
                                                    const __half* __restrict__ Kh,
                                                    const float* __restrict__ avec,
                                                    const float* __restrict__ bvec,
                                                    const float* __restrict__ pos,
                                                    const float* __restrict__ alpha) {
    int bb = blockIdx.y;
    int i0 = blockIdx.x * 16;
    __shared__ float as_[16], ys[16], xs2[16];
    int t = threadIdx.x;
    if (t < 16) {
        int i = i0 + t;
        as_[t] = (i < NP1) ? avec[(size_t)bb * VSTR + i] : 0.f;
        if (i < NN) {
            ys[t]  = pos[((size_t)bb * NN + i) * 2 + 0];
            xs2[t] = pos[((size_t)bb * NN + i) * 2 + 1];
        } else {
            ys[t] = 1e9f; xs2[t] = 1e9f;
        }
    }
    __syncthreads();
    float E = __expf(alpha[0]);
    float* outb = out + (size_t)bb * NP1 * NP1;
    const __half* Khb = Kh + (size_t)bb * NN * NN;
    for (int j = t; j < NP1; j += 256) {
        float bj = bvec[(size_t)bb * VSTR + j];
        bool jin = (j < NN);
        float yj = 0.f, xj = 0.f;
        if (jin) {
            yj = pos[((size_t)bb * NN + j) * 2 + 0];
            xj = pos[((size_t)bb * NN + j) * 2 + 1];
        }
#pragma unroll 1
        for (int r = 0; r < 16; r++) {
            int i = i0 + r;
            if (i >= NP1) break;
            size_t idx = (size_t)i * NP1 + j;
            float v;
            if (i < NN && jin) {
                float Kv = F16 ? __half2float(Khb[(size_t)i * NN + j]) : outb[idx];
                bool c = (fabsf(ys[r] - yj) <= 0.1f) && (fabsf(xs2[r] - xj) <= 0.1f);
                v = c ? Kv * as_[r] * bj * 4096.0f : 0.0f;
            } else {
                v = E * as_[r] * bj * 4096.0f;
            }
            outb[idx] = v;
        }
    }
}

extern "C" void kernel_launch(void* const* d_in, const int* in_sizes, int n_in,
                              void* d_out, int out_size, void* d_ws, size_t ws_size,
                              hipStream_t stream) {
    const float* F     = (const float*)d_in[0];  // (B, D, N)
    const float* pos   = (const float*)d_in[1];  // (B, N, 2)
    const float* alpha = (const float*)d_in[3];  // (1,)
    float* out = (float*)d_out;
    float* ws  = (float*)d_ws;

    float* avec = ws;
    float* bvec = ws + BN * VSTR;
    float* sums = ws + 2 * BN * VSTR;                 // 41*BN floats
    int*   bar  = (int*)(sums + 41 * BN);             // 8 ints (32B, keeps 16B align)
    __half* Kh  = (__half*)(bar + 8);

    size_t need = (size_t)(2 * BN * VSTR + 41 * BN + 8) * 4 + (size_t)BN * NN * NN * 2;
    bool f16 = (ws_size >= need);

    hipLaunchKernelGGL(init_kernel, dim3(64), dim3(256), 0, stream, bvec, BN * VSTR,
                       sums, bar);

    if (f16) {
        hipLaunchKernelGGL((build_k_kernel<true>), dim3(32, 32, BN), dim3(256), 0, stream,
                           F, out, Kh);
        const __half* Kp = Kh;
        float* ap = avec; float* bp = bvec; float* sp = sums; int* brp = bar;
        const float* alp = alpha;
        void* params[6] = {(void*)&Kp, (void*)&ap, (void*)&bp, (void*)&sp,
                           (void*)&brp, (void*)&alp};
        hipLaunchCooperativeKernel((const void*)sink_persist, dim3(NBLK), dim3(1024),
                                   params, 0, stream);
        hipLaunchKernelGGL((final_kernel<true>), dim3((NP1 + 15) / 16, BN), dim3(256), 0,
                           stream, out, Kh, avec, bvec, pos, alpha);
    } else {
        hipLaunchKernelGGL((build_k_kernel<false>), dim3(32, 32, BN), dim3(256), 0, stream,
                           F, out, Kh);
        const float* xin = bvec;
        float* xout = avec;
        for (int p = 1; p <= 2 * NITER; p++) {
            hipLaunchKernelGGL(sink_pass_f32, dim3(NN / 16, BN), dim3(256), 0, stream,
                               out, xin, xout, sums + (p - 1) * BN, sums + p * BN, alpha);
            float* tmp = (float*)xin; xin = xout; xout = tmp;
        }
        hipLaunchKernelGGL((final_kernel<false>), dim3((NP1 + 15) / 16, BN), dim3(256), 0,
                           stream, out, Kh, avec, bvec, pos, alpha);
    }
}

// Round 9
// 796.714 us; speedup vs baseline: 1.6199x; 1.6199x over previous
//
#include <hip/hip_runtime.h>
#include <math.h>

#define BN    8
#define NN    2048
#define NP1   2049
#define VSTR  2056   // padded a/b vector stride (floats), 16B-aligned rows
#define DD    256
#define NITER 20
#define NBLK  256    // persistent grid size, 1 block/CU

typedef float f32x2 __attribute__((ext_vector_type(2)));

// ws layout: a[BN*VSTR] f32 | b[BN*VSTR] f32 | sums[41*BN] f32 | bar[8] i32 | K8[BN*NN*NN] fp8

__global__ void init_kernel(float* __restrict__ bvec, int nb, float* __restrict__ sums,
                            int* __restrict__ bar) {
    int tid = blockIdx.x * blockDim.x + threadIdx.x;
    int stride = gridDim.x * blockDim.x;
    for (int i = tid; i < nb; i += stride) bvec[i] = 1.0f;            // v0 = 0 -> b = 1
    for (int i = tid; i < 41 * BN; i += stride) sums[i] = (i < BN) ? (float)NN : 0.0f;
    if (tid < 8) bar[tid] = 0;
}

// K = exp(F^T F / 16), diag = 0. FP8 variant packs 4 cols -> u32 (OCP e4m3 HW cvt)
// into K8 (stride NN); fp32 variant writes into out's NxN (stride NP1). tj>=ti only.
template <bool FP8>
__global__ __launch_bounds__(256) void build_k_kernel(const float* __restrict__ F,
                                                      float* __restrict__ out,
                                                      unsigned char* __restrict__ K8) {
    int ti = blockIdx.x, tj = blockIdx.y, bb = blockIdx.z;
    if (tj < ti) return;
    __shared__ float As[32][64];
    __shared__ float Bs[32][64];
    int t  = threadIdx.x;
    int tx = t & 15, ty = t >> 4;
    float acc[4][4] = {};
    const float* Fb = F + (size_t)bb * DD * NN;
    int i0 = ti * 64, j0 = tj * 64;
    for (int k0 = 0; k0 < DD; k0 += 32) {
#pragma unroll
        for (int v = 0; v < 2; v++) {
            int f = t + 256 * v;
            int row = f >> 4, c4 = (f & 15) * 4;
            *(float4*)&As[row][c4] = *(const float4*)&Fb[(size_t)(k0 + row) * NN + i0 + c4];
            *(float4*)&Bs[row][c4] = *(const float4*)&Fb[(size_t)(k0 + row) * NN + j0 + c4];
        }
        __syncthreads();
#pragma unroll
        for (int k = 0; k < 32; k++) {
            float4 av = *(float4*)&As[k][ty * 4];
            float4 bv = *(float4*)&Bs[k][tx * 4];
            float ar[4] = {av.x, av.y, av.z, av.w};
            float br[4] = {bv.x, bv.y, bv.z, bv.w};
#pragma unroll
            for (int r = 0; r < 4; r++)
#pragma unroll
                for (int c = 0; c < 4; c++)
                    acc[r][c] = fmaf(ar[r], br[c], acc[r][c]);
        }
        __syncthreads();
    }
#pragma unroll
    for (int r = 0; r < 4; r++) {
        int i = i0 + ty * 4 + r;
        float kvl[4];
#pragma unroll
        for (int c = 0; c < 4; c++) {
            int j = j0 + tx * 4 + c;
            kvl[c] = (i == j) ? 0.0f : __expf(acc[r][c] * 0.0625f);  // 1/sqrt(256)
        }
        if constexpr (FP8) {
            unsigned w = __builtin_amdgcn_cvt_pk_fp8_f32(kvl[0], kvl[1], 0, false);
            w = __builtin_amdgcn_cvt_pk_fp8_f32(kvl[2], kvl[3], w, true);
            unsigned char* K8b = K8 + (size_t)bb * NN * NN;
            *(unsigned*)(K8b + (size_t)i * NN + (j0 + tx * 4)) = w;
            if (tj > ti) {
#pragma unroll
                for (int c = 0; c < 4; c++)
                    K8b[(size_t)(j0 + tx * 4 + c) * NN + i] =
                        (unsigned char)((w >> (8 * c)) & 0xff);
            }
        } else {
            float* outb = out + (size_t)bb * NP1 * NP1;
#pragma unroll
            for (int c = 0; c < 4; c++) {
                int j = j0 + tx * 4 + c;
                outb[(size_t)i * NP1 + j] = kvl[c];
                if (tj > ti) outb[(size_t)j * NP1 + i] = kvl[c];
            }
        }
    }
}

// Persistent Sinkhorn with the 128 KB fp8 K-shard resident in LDS (R4-R8
// register-residency attempts all lost to the RA; LDS residency is structural).
// 256 blocks x 1024 threads = 1 block/CU. Block b: batch=b>>5, rows
// [(b&31)*64,+64). Thread: row=tid>>4, cols [(tid&15)*128,+128).
// K-shard XOR-swizzled (byte bits[6:4] ^= seg&7) so the seg*128-stride
// ds_read_b128 pattern spreads across all 32 banks (G4 fix).
// Grid barrier: R7's slim leaf barrier (tid0 release-add + spin + acquire).
__global__ __launch_bounds__(1024) void sink_persist(const unsigned char* __restrict__ K8,
                                                     float* __restrict__ avec,
                                                     float* __restrict__ bvec,
                                                     float* __restrict__ sums,
                                                     int* __restrict__ bar,
                                                     const float* __restrict__ alpha) {
    int blk   = blockIdx.x;
    int batch = blk >> 5;
    int rb    = blk & 31;
    int tid   = threadIdx.x;
    int seg   = tid & 15;
    int row   = tid >> 4;          // row within the 64-row shard
    int grow  = rb * 64 + row;     // global row

    __shared__ __align__(16) unsigned char Ks[64 * 2048];   // 128 KB fp8 shard
    __shared__ float xs[16 * 132];                          // padded x stage
    __shared__ float wsum[16];

    // one-time stage: global (linear) -> LDS (swizzled), 128 B/thread x 8
    {
        const int4* gsrc = (const int4*)(K8 + ((size_t)batch * NN + (size_t)rb * 64) * NN);
#pragma unroll
        for (int q = 0; q < 8; q++) {
            int idx = q * 1024 + tid;
            int4 v = gsrc[idx];
            int g = idx * 16;
            int r_ = g >> 11, bir = g & 2047;
            *(int4*)&Ks[r_ * 2048 + (bir ^ (((bir >> 7) & 7) << 4))] = v;
        }
    }   // first pass's __syncthreads() covers this staging

    float* av = avec + (size_t)batch * VSTR;
    float* bv = bvec + (size_t)batch * VSTR;
    float E    = __expf(alpha[0]);
    float binA = 0.f, binB = 1.0f;
    float S_in = 2048.0f;            // sum of vector entering current pass
    int   ep   = 0;
    const float4* xp4 = (const float4*)(xs + seg * 132);
    const int kbase = row * 2048;
    const int sb    = seg * 128;
    const int sx    = (seg & 7) << 4;

#define MAC16(KI, ACC)                                                          \
    {                                                                           \
        int4 kv = *(const int4*)&Ks[kbase + ((sb + (KI) * 16) ^ sx)];           \
        float4 xa = xp4[(KI) * 4 + 0], xb = xp4[(KI) * 4 + 1];                  \
        float4 xc = xp4[(KI) * 4 + 2], xd = xp4[(KI) * 4 + 3];                  \
        f32x2 p0 = __builtin_amdgcn_cvt_pk_f32_fp8(kv.x, false);                \
        f32x2 p1 = __builtin_amdgcn_cvt_pk_f32_fp8(kv.x, true);                 \
        f32x2 p2 = __builtin_amdgcn_cvt_pk_f32_fp8(kv.y, false);                \
        f32x2 p3 = __builtin_amdgcn_cvt_pk_f32_fp8(kv.y, true);                 \
        f32x2 p4 = __builtin_amdgcn_cvt_pk_f32_fp8(kv.z, false);                \
        f32x2 p5 = __builtin_amdgcn_cvt_pk_f32_fp8(kv.z, true);                 \
        f32x2 p6 = __builtin_amdgcn_cvt_pk_f32_fp8(kv.w, false);                \
        f32x2 p7 = __builtin_amdgcn_cvt_pk_f32_fp8(kv.w, true);                 \
        ACC = fmaf(p0.x, xa.x, ACC); ACC = fmaf(p0.y, xa.y, ACC);               \
        ACC = fmaf(p1.x, xa.z, ACC); ACC = fmaf(p1.y, xa.w, ACC);               \
        ACC = fmaf(p2.x, xb.x, ACC); ACC = fmaf(p2.y, xb.y, ACC);               \
        ACC = fmaf(p3.x, xb.z, ACC); ACC = fmaf(p3.y, xb.w, ACC);               \
        ACC = fmaf(p4.x, xc.x, ACC); ACC = fmaf(p4.y, xc.y, ACC);               \
        ACC = fmaf(p5.x, xc.z, ACC); ACC = fmaf(p5.y, xc.w, ACC);               \
        ACC = fmaf(p6.x, xd.x, ACC); ACC = fmaf(p6.y, xd.y, ACC);               \
        ACC = fmaf(p7.x, xd.z, ACC); ACC = fmaf(p7.y, xd.w, ACC);               \
    }

#define SINK_PASS(XIN, XOUT, BIN_IN, BIN_OUT, P, LAST)                          \
    {                                                                           \
        {   /* stage XIN[0..2048) into LDS (coalesced float2) */                \
            float2 v = ((const float2*)(XIN))[tid];                             \
            int j = tid * 2;                                                    \
            float* d = xs + ((j >> 7) * 132 + (j & 127));                       \
            d[0] = v.x; d[1] = v.y;                                             \
        }                                                                       \
        __syncthreads();                                                        \
        float dot0 = 0.f, dot1 = 0.f;                                           \
        MAC16(0, dot0) MAC16(1, dot1) MAC16(2, dot0) MAC16(3, dot1)             \
        MAC16(4, dot0) MAC16(5, dot1) MAC16(6, dot0) MAC16(7, dot1)             \
        float dot = dot0 + dot1;                                                \
        dot += __shfl_xor(dot, 1);                                              \
        dot += __shfl_xor(dot, 2);                                              \
        dot += __shfl_xor(dot, 4);                                              \
        dot += __shfl_xor(dot, 8);                                              \
        float val = (1.0f / 4096.0f) / (dot + E * (BIN_IN));                    \
        BIN_OUT = 0.5f / (E * (S_in + (BIN_IN)));                               \
        float ys = val;                                                         \
        ys += __shfl_xor(ys, 16);                                               \
        ys += __shfl_xor(ys, 32);                                               \
        if ((tid & 15) == 0) (XOUT)[grow] = val;                                \
        if ((tid & 63) == 0) wsum[tid >> 6] = ys;                               \
        __syncthreads();                                                        \
        if (!(LAST)) {                                                          \
            ep += NBLK;                                                         \
            if (tid == 0) {                                                     \
                float s = 0.f;                                                  \
                _Pragma("unroll")                                               \
                for (int w = 0; w < 16; w++) s += wsum[w];                      \
                atomicAdd(&sums[(P) * BN + batch], s);                          \
                __hip_atomic_fetch_add(bar, 1, __ATOMIC_RELEASE,                \
                                       __HIP_MEMORY_SCOPE_AGENT);               \
                while (__hip_atomic_load(bar, __ATOMIC_RELAXED,                 \
                                         __HIP_MEMORY_SCOPE_AGENT) < ep)        \
                    __builtin_amdgcn_s_sleep(1);                                \
                __builtin_amdgcn_fence(__ATOMIC_ACQUIRE, "agent");              \
            }                                                                   \
            __syncthreads();                                                    \
            S_in = sums[(P) * BN + batch];                                      \
        }                                                                       \
    }

    for (int it2 = 0; it2 < NITER; it2++) {
        int p = 2 * it2 + 1;
        SINK_PASS(bv, av, binB, binA, p, false);
        SINK_PASS(av, bv, binA, binB, p + 1, (it2 == NITER - 1));
    }
#undef SINK_PASS
#undef MAC16

    if (tid == 0) { av[NN] = binA; bv[NN] = binB; }
}

// fp32 fallback pass (K in d_out, stride NP1) for ws-too-small case.
__global__ __launch_bounds__(256) void sink_pass_f32(const float* __restrict__ K,
                                                     const float* __restrict__ xin,
                                                     float* __restrict__ xout,
                                                     const float* __restrict__ sum_in,
                                                     float* __restrict__ sum_out,
                                                     const float* __restrict__ alpha) {
    int bb = blockIdx.y;
    int i0 = blockIdx.x * 16;
    __shared__ float xsl[NN];
    __shared__ float rowa[16];
    const float* xinb = xin + (size_t)bb * VSTR;
    int t = threadIdx.x;
    for (int j = t; j < NN; j += 256) xsl[j] = xinb[j];
    __syncthreads();
    float E  = __expf(alpha[0]);
    float xN = xinb[NN];
    int wave = t >> 6, lane = t & 63;
    const float* Kb = K + (size_t)bb * NP1 * NP1;
    for (int r = wave; r < 16; r += 4) {
        int i = i0 + r;
        const float* rowp = Kb + (size_t)i * NP1;
        float acc = 0.f;
        for (int j = lane; j < NN; j += 64) acc = fmaf(rowp[j], xsl[j], acc);
#pragma unroll
        for (int off = 32; off >= 1; off >>= 1) acc += __shfl_xor(acc, off);
        if (lane == 0) {
            float v = (1.0f / 4096.0f) / (acc + E * xN);
            xout[(size_t)bb * VSTR + i] = v;
            rowa[r] = v;
        }
    }
    __syncthreads();
    if (t == 0) {
        float s = 0.f;
#pragma unroll
        for (int r = 0; r < 16; r++) s += rowa[r];
        atomicAdd(sum_out + bb, s);
        if (blockIdx.x == 0) xout[(size_t)bb * VSTR + NN] = 0.5f / (E * (sum_in[bb] + xN));
    }
}

// out[i,j] = K*a_i*b_j*4096*cost (i,j<N), bins use E. FP8: K from K8; else in-place.
template <bool FP8>
__global__ __launch_bounds__(256) void final_kernel(float* __restrict__ out,
                                                    const unsigned char* __restrict__ K8,
                                                    const float* __restrict__ avec,
                                                    const float* __restrict__ bvec,
                                                    const float* __restrict__ pos,
                                                    const float* __restrict__ alpha) {
    int bb = blockIdx.y;
    int i0 = blockIdx.x * 16;
    __shared__ float as_[16], ys[16], xs2[16];
    int t = threadIdx.x;
    if (t < 16) {
        int i = i0 + t;
        as_[t] = (i < NP1) ? avec[(size_t)bb * VSTR + i] : 0.f;
        if (i < NN) {
            ys[t]  = pos[((size_t)bb * NN + i) * 2 + 0];
            xs2[t] = pos[((size_t)bb * NN + i) * 2 + 1];
        } else {
            ys[t] = 1e9f; xs2[t] = 1e9f;
        }
    }
    __syncthreads();
    float E = __expf(alpha[0]);
    float* outb = out + (size_t)bb * NP1 * NP1;
    const unsigned char* K8b = K8 + (size_t)bb * NN * NN;
    for (int j = t; j < NP1; j += 256) {
        float bj = bvec[(size_t)bb * VSTR + j];
        bool jin = (j < NN);
        float yj = 0.f, xj = 0.f;
        if (jin) {
            yj = pos[((size_t)bb * NN + j) * 2 + 0];
            xj = pos[((size_t)bb * NN + j) * 2 + 1];
        }
#pragma unroll 1
        for (int r = 0; r < 16; r++) {
            int i = i0 + r;
            if (i >= NP1) break;
            size_t idx = (size_t)i * NP1 + j;
            float v;
            if (i < NN && jin) {
                float Kv;
                if constexpr (FP8)
                    Kv = __builtin_amdgcn_cvt_f32_fp8((int)K8b[(size_t)i * NN + j], 0);
                else
                    Kv = outb[idx];
                bool c = (fabsf(ys[r] - yj) <= 0.1f) && (fabsf(xs2[r] - xj) <= 0.1f);
                v = c ? Kv * as_[r] * bj * 4096.0f : 0.0f;
            } else {
                v = E * as_[r] * bj * 4096.0f;
            }
            outb[idx] = v;
        }
    }
}

extern "C" void kernel_launch(void* const* d_in, const int* in_sizes, int n_in,
                              void* d_out, int out_size, void* d_ws, size_t ws_size,
                              hipStream_t stream) {
    const float* F     = (const float*)d_in[0];  // (B, D, N)
    const float* pos   = (const float*)d_in[1];  // (B, N, 2)
    const float* alpha = (const float*)d_in[3];  // (1,)
    float* out = (float*)d_out;
    float* ws  = (float*)d_ws;

    float* avec = ws;
    float* bvec = ws + BN * VSTR;
    float* sums = ws + 2 * BN * VSTR;                 // 41*BN floats
    int*   bar  = (int*)(sums + 41 * BN);             // 8 ints (32B, keeps 16B align)
    unsigned char* K8 = (unsigned char*)(bar + 8);    // 33.5 MB fp8

    size_t need = (size_t)(2 * BN * VSTR + 41 * BN + 8) * 4 + (size_t)BN * NN * NN;
    bool fp8 = (ws_size >= need);

    hipLaunchKernelGGL(init_kernel, dim3(64), dim3(256), 0, stream, bvec, BN * VSTR,
                       sums, bar);

    if (fp8) {
        hipLaunchKernelGGL((build_k_kernel<true>), dim3(32, 32, BN), dim3(256), 0, stream,
                           F, out, K8);
        const unsigned char* Kp = K8;
        float* ap = avec; float* bp = bvec; float* sp = sums; int* brp = bar;
        const float* alp = alpha;
        void* params[6] = {(void*)&Kp, (void*)&ap, (void*)&bp, (void*)&sp,
                           (void*)&brp, (void*)&alp};
        hipLaunchCooperativeKernel((const void*)sink_persist, dim3(NBLK), dim3(1024),
                                   params, 0, stream);
        hipLaunchKernelGGL((final_kernel<true>), dim3((NP1 + 15) / 16, BN), dim3(256), 0,
                           stream, out, K8, avec, bvec, pos, alpha);
    } else {
        hipLaunchKernelGGL((build_k_kernel<false>), dim3(32, 32, BN), dim3(256), 0, stream,
                           F, out, K8);
        const float* xin = bvec;
        float* xout = avec;
        for (int p = 1; p <= 2 * NITER; p++) {
            hipLaunchKernelGGL(sink_pass_f32, dim3(NN / 16, BN), dim3(256), 0, stream,
                               out, xin, xout, sums + (p - 1) * BN, sums + p * BN, alpha);
            float* tmp = (float*)xin; xin = xout; xout = tmp;
        }
        hipLaunchKernelGGL((final_kernel<false>), dim3((NP1 + 15) / 16, BN), dim3(256), 0,
                           stream, out, K8, avec, bvec, pos, alpha);
    }
}

// Round 10
// 593.844 us; speedup vs baseline: 2.1733x; 1.3416x over previous
//
#include <hip/hip_runtime.h>
#include <math.h>

#define BN    8
#define NN    2048
#define NP1   2049
#define VSTR  2056   // padded a/b vector stride (floats), 16B-aligned rows
#define DD    256
#define NITER 20
#define NBLK  256    // persistent grid size, 1 block/CU
#define GRP   32     // blocks per batch (independent barrier group)

typedef float f32x2 __attribute__((ext_vector_type(2)));

// ws layout: a[BN*VSTR] f32 | b[BN*VSTR] f32 | sums[41*BN] f32 | bar[8*32] i32 | K8[BN*NN*NN] fp8

__global__ void init_kernel(float* __restrict__ bvec, int nb, float* __restrict__ sums,
                            int* __restrict__ bar) {
    int tid = blockIdx.x * blockDim.x + threadIdx.x;
    int stride = gridDim.x * blockDim.x;
    for (int i = tid; i < nb; i += stride) bvec[i] = 1.0f;            // v0 = 0 -> b = 1
    for (int i = tid; i < 41 * BN; i += stride) sums[i] = (i < BN) ? (float)NN : 0.0f;
    if (tid < BN * GRP) bar[tid] = 0;
}

// K = exp(F^T F / 16), diag = 0. FP8 variant packs 4 cols -> u32 (OCP e4m3 HW cvt)
// into K8 (stride NN); fp32 variant writes into out's NxN (stride NP1). tj>=ti only.
template <bool FP8>
__global__ __launch_bounds__(256) void build_k_kernel(const float* __restrict__ F,
                                                      float* __restrict__ out,
                                                      unsigned char* __restrict__ K8) {
    int ti = blockIdx.x, tj = blockIdx.y, bb = blockIdx.z;
    if (tj < ti) return;
    __shared__ float As[32][64];
    __shared__ float Bs[32][64];
    int t  = threadIdx.x;
    int tx = t & 15, ty = t >> 4;
    float acc[4][4] = {};
    const float* Fb = F + (size_t)bb * DD * NN;
    int i0 = ti * 64, j0 = tj * 64;
    for (int k0 = 0; k0 < DD; k0 += 32) {
#pragma unroll
        for (int v = 0; v < 2; v++) {
            int f = t + 256 * v;
            int row = f >> 4, c4 = (f & 15) * 4;
            *(float4*)&As[row][c4] = *(const float4*)&Fb[(size_t)(k0 + row) * NN + i0 + c4];
            *(float4*)&Bs[row][c4] = *(const float4*)&Fb[(size_t)(k0 + row) * NN + j0 + c4];
        }
        __syncthreads();
#pragma unroll
        for (int k = 0; k < 32; k++) {
            float4 av = *(float4*)&As[k][ty * 4];
            float4 bv = *(float4*)&Bs[k][tx * 4];
            float ar[4] = {av.x, av.y, av.z, av.w};
            float br[4] = {bv.x, bv.y, bv.z, bv.w};
#pragma unroll
            for (int r = 0; r < 4; r++)
#pragma unroll
                for (int c = 0; c < 4; c++)
                    acc[r][c] = fmaf(ar[r], br[c], acc[r][c]);
        }
        __syncthreads();
    }
#pragma unroll
    for (int r = 0; r < 4; r++) {
        int i = i0 + ty * 4 + r;
        float kvl[4];
#pragma unroll
        for (int c = 0; c < 4; c++) {
            int j = j0 + tx * 4 + c;
            kvl[c] = (i == j) ? 0.0f : __expf(acc[r][c] * 0.0625f);  // 1/sqrt(256)
        }
        if constexpr (FP8) {
            unsigned w = __builtin_amdgcn_cvt_pk_fp8_f32(kvl[0], kvl[1], 0, false);
            w = __builtin_amdgcn_cvt_pk_fp8_f32(kvl[2], kvl[3], w, true);
            unsigned char* K8b = K8 + (size_t)bb * NN * NN;
            *(unsigned*)(K8b + (size_t)i * NN + (j0 + tx * 4)) = w;
            if (tj > ti) {
#pragma unroll
                for (int c = 0; c < 4; c++)
                    K8b[(size_t)(j0 + tx * 4 + c) * NN + i] =
                        (unsigned char)((w >> (8 * c)) & 0xff);
            }
        } else {
            float* outb = out + (size_t)bb * NP1 * NP1;
#pragma unroll
            for (int c = 0; c < 4; c++) {
                int j = j0 + tx * 4 + c;
                outb[(size_t)i * NP1 + j] = kvl[c];
                if (tj > ti) outb[(size_t)j * NP1 + i] = kvl[c];
            }
        }
    }
}

// Persistent Sinkhorn with the 128 KB fp8 K-shard resident in LDS.
// R9 post-mortem: 9 of 13.3 us/pass was the 256-block single-line grid
// barrier (serialized same-line RMWs + whole-chip straggler wait). Batches
// are fully independent -> 8 per-batch 32-block barriers, each counter on
// its own 128-B line. 256 blocks x 1024 threads = 1 block/CU.
// Block b: batch=b>>5, rows [(b&31)*64,+64). Thread: row=tid>>4, cols
// [(tid&15)*128,+128). K-shard XOR-swizzled (byte bits[6:4] ^= seg&7).
__global__ __launch_bounds__(1024) void sink_persist(const unsigned char* __restrict__ K8,
                                                     float* __restrict__ avec,
                                                     float* __restrict__ bvec,
                                                     float* __restrict__ sums,
                                                     int* __restrict__ bar,
                                                     const float* __restrict__ alpha) {
    int blk   = blockIdx.x;
    int batch = blk >> 5;
    int rb    = blk & 31;
    int tid   = threadIdx.x;
    int seg   = tid & 15;
    int row   = tid >> 4;          // row within the 64-row shard
    int grow  = rb * 64 + row;     // global row

    __shared__ __align__(16) unsigned char Ks[64 * 2048];   // 128 KB fp8 shard
    __shared__ float xs[16 * 132];                          // padded x stage
    __shared__ float wsum[16];

    // one-time stage: global (linear) -> LDS (swizzled), 128 B/thread x 8
    {
        const int4* gsrc = (const int4*)(K8 + ((size_t)batch * NN + (size_t)rb * 64) * NN);
#pragma unroll
        for (int q = 0; q < 8; q++) {
            int idx = q * 1024 + tid;
            int4 v = gsrc[idx];
            int g = idx * 16;
            int r_ = g >> 11, bir = g & 2047;
            *(int4*)&Ks[r_ * 2048 + (bir ^ (((bir >> 7) & 7) << 4))] = v;
        }
    }   // first pass's __syncthreads() covers this staging

    float* av = avec + (size_t)batch * VSTR;
    float* bv = bvec + (size_t)batch * VSTR;
    int*   gbar = bar + batch * GRP;   // this batch's barrier line (128 B apart)
    float E    = __expf(alpha[0]);
    float binA = 0.f, binB = 1.0f;
    float S_in = 2048.0f;            // sum of vector entering current pass
    int   ep   = 0;
    const float4* xp4 = (const float4*)(xs + seg * 132);
    const int kbase = row * 2048;
    const int sb    = seg * 128;
    const int sx    = (seg & 7) << 4;

#define MAC16(KI, ACC)                                                          \
    {                                                                           \
        int4 kv = *(const int4*)&Ks[kbase + ((sb + (KI) * 16) ^ sx)];           \
        float4 xa = xp4[(KI) * 4 + 0], xb = xp4[(KI) * 4 + 1];                  \
        float4 xc = xp4[(KI) * 4 + 2], xd = xp4[(KI) * 4 + 3];                  \
        f32x2 p0 = __builtin_amdgcn_cvt_pk_f32_fp8(kv.x, false);                \
        f32x2 p1 = __builtin_amdgcn_cvt_pk_f32_fp8(kv.x, true);                 \
        f32x2 p2 = __builtin_amdgcn_cvt_pk_f32_fp8(kv.y, false);                \
        f32x2 p3 = __builtin_amdgcn_cvt_pk_f32_fp8(kv.y, true);                 \
        f32x2 p4 = __builtin_amdgcn_cvt_pk_f32_fp8(kv.z, false);                \
        f32x2 p5 = __builtin_amdgcn_cvt_pk_f32_fp8(kv.z, true);                 \
        f32x2 p6 = __builtin_amdgcn_cvt_pk_f32_fp8(kv.w, false);                \
        f32x2 p7 = __builtin_amdgcn_cvt_pk_f32_fp8(kv.w, true);                 \
        ACC = fmaf(p0.x, xa.x, ACC); ACC = fmaf(p0.y, xa.y, ACC);               \
        ACC = fmaf(p1.x, xa.z, ACC); ACC = fmaf(p1.y, xa.w, ACC);               \
        ACC = fmaf(p2.x, xb.x, ACC); ACC = fmaf(p2.y, xb.y, ACC);               \
        ACC = fmaf(p3.x, xb.z, ACC); ACC = fmaf(p3.y, xb.w, ACC);               \
        ACC = fmaf(p4.x, xc.x, ACC); ACC = fmaf(p4.y, xc.y, ACC);               \
        ACC = fmaf(p5.x, xc.z, ACC); ACC = fmaf(p5.y, xc.w, ACC);               \
        ACC = fmaf(p6.x, xd.x, ACC); ACC = fmaf(p6.y, xd.y, ACC);               \
        ACC = fmaf(p7.x, xd.z, ACC); ACC = fmaf(p7.y, xd.w, ACC);               \
    }

#define SINK_PASS(XIN, XOUT, BIN_IN, BIN_OUT, P, LAST)                          \
    {                                                                           \
        {   /* stage XIN[0..2048) into LDS (coalesced float2) */                \
            float2 v = ((const float2*)(XIN))[tid];                             \
            int j = tid * 2;                                                    \
            float* d = xs + ((j >> 7) * 132 + (j & 127));                       \
            d[0] = v.x; d[1] = v.y;                                             \
        }                                                                       \
        __syncthreads();                                                        \
        float dot0 = 0.f, dot1 = 0.f;                                           \
        MAC16(0, dot0) MAC16(1, dot1) MAC16(2, dot0) MAC16(3, dot1)             \
        MAC16(4, dot0) MAC16(5, dot1) MAC16(6, dot0) MAC16(7, dot1)             \
        float dot = dot0 + dot1;                                                \
        dot += __shfl_xor(dot, 1);                                              \
        dot += __shfl_xor(dot, 2);                                              \
        dot += __shfl_xor(dot, 4);                                              \
        dot += __shfl_xor(dot, 8);                                              \
        float val = (1.0f / 4096.0f) / (dot + E * (BIN_IN));                    \
        BIN_OUT = 0.5f / (E * (S_in + (BIN_IN)));                               \
        float ys = val;                                                         \
        ys += __shfl_xor(ys, 16);                                               \
        ys += __shfl_xor(ys, 32);                                               \
        if ((tid & 15) == 0) (XOUT)[grow] = val;                                \
        if ((tid & 63) == 0) wsum[tid >> 6] = ys;                               \
        __syncthreads();                                                        \
        if (!(LAST)) {                                                          \
            ep += GRP;                                                          \
            if (tid == 0) {                                                     \
                float s = 0.f;                                                  \
                _Pragma("unroll")                                               \
                for (int w = 0; w < 16; w++) s += wsum[w];                      \
                atomicAdd(&sums[(P) * BN + batch], s);                          \
                __hip_atomic_fetch_add(gbar, 1, __ATOMIC_RELEASE,               \
                                       __HIP_MEMORY_SCOPE_AGENT);               \
                while (__hip_atomic_load(gbar, __ATOMIC_RELAXED,                \
                                         __HIP_MEMORY_SCOPE_AGENT) < ep)        \
                    __builtin_amdgcn_s_sleep(1);                                \
                __builtin_amdgcn_fence(__ATOMIC_ACQUIRE, "agent");              \
            }                                                                   \
            __syncthreads();                                                    \
            S_in = sums[(P) * BN + batch];                                      \
        }                                                                       \
    }

    for (int it2 = 0; it2 < NITER; it2++) {
        int p = 2 * it2 + 1;
        SINK_PASS(bv, av, binB, binA, p, false);
        SINK_PASS(av, bv, binA, binB, p + 1, (it2 == NITER - 1));
    }
#undef SINK_PASS
#undef MAC16

    if (tid == 0) { av[NN] = binA; bv[NN] = binB; }
}

// fp32 fallback pass (K in d_out, stride NP1) for ws-too-small case.
__global__ __launch_bounds__(256) void sink_pass_f32(const float* __restrict__ K,
                                                     const float* __restrict__ xin,
                                                     float* __restrict__ xout,
                                                     const float* __restrict__ sum_in,
                                                     float* __restrict__ sum_out,
                                                     const float* __restrict__ alpha) {
    int bb = blockIdx.y;
    int i0 = blockIdx.x * 16;
    __shared__ float xsl[NN];
    __shared__ float rowa[16];
    const float* xinb = xin + (size_t)bb * VSTR;
    int t = threadIdx.x;
    for (int j = t; j < NN; j += 256) xsl[j] = xinb[j];
    __syncthreads();
    float E  = __expf(alpha[0]);
    float xN = xinb[NN];
    int wave = t >> 6, lane = t & 63;
    const float* Kb = K + (size_t)bb * NP1 * NP1;
    for (int r = wave; r < 16; r += 4) {
        int i = i0 + r;
        const float* rowp = Kb + (size_t)i * NP1;
        float acc = 0.f;
        for (int j = lane; j < NN; j += 64) acc = fmaf(rowp[j], xsl[j], acc);
#pragma unroll
        for (int off = 32; off >= 1; off >>= 1) acc += __shfl_xor(acc, off);
        if (lane == 0) {
            float v = (1.0f / 4096.0f) / (acc + E * xN);
            xout[(size_t)bb * VSTR + i] = v;
            rowa[r] = v;
        }
    }
    __syncthreads();
    if (t == 0) {
        float s = 0.f;
#pragma unroll
        for (int r = 0; r < 16; r++) s += rowa[r];
        atomicAdd(sum_out + bb, s);
        if (blockIdx.x == 0) xout[(size_t)bb * VSTR + NN] = 0.5f / (E * (sum_in[bb] + xN));
    }
}

// out[i,j] = K*a_i*b_j*4096*cost (i,j<N), bins use E. FP8: K from K8; else in-place.
template <bool FP8>
__global__ __launch_bounds__(256) void final_kernel(float* __restrict__ out,
                                                    const unsigned char* __restrict__ K8,
                                                    const float* __restrict__ avec,
                                                    const float* __restrict__ bvec,
                                                    const float* __restrict__ pos,
                                                    const float* __restrict__ alpha) {
    int bb = blockIdx.y;
    int i0 = blockIdx.x * 16;
    __shared__ float as_[16], ys[16], xs2[16];
    int t = threadIdx.x;
    if (t < 16) {
        int i = i0 + t;
        as_[t] = (i < NP1) ? avec[(size_t)bb * VSTR + i] : 0.f;
        if (i < NN) {
            ys[t]  = pos[((size_t)bb * NN + i) * 2 + 0];
            xs2[t] = pos[((size_t)bb * NN + i) * 2 + 1];
        } else {
            ys[t] = 1e9f; xs2[t] = 1e9f;
        }
    }
    __syncthreads();
    float E = __expf(alpha[0]);
    float* outb = out + (size_t)bb * NP1 * NP1;
    const unsigned char* K8b = K8 + (size_t)bb * NN * NN;
    for (int j = t; j < NP1; j += 256) {
        float bj = bvec[(size_t)bb * VSTR + j];
        bool jin = (j < NN);
        float yj = 0.f, xj = 0.f;
        if (jin) {
            yj = pos[((size_t)bb * NN + j) * 2 + 0];
            xj = pos[((size_t)bb * NN + j) * 2 + 1];
        }
#pragma unroll 1
        for (int r = 0; r < 16; r++) {
            int i = i0 + r;
            if (i >= NP1) break;
            size_t idx = (size_t)i * NP1 + j;
            float v;
            if (i < NN && jin) {
                float Kv;
                if constexpr (FP8)
                    Kv = __builtin_amdgcn_cvt_f32_fp8((int)K8b[(size_t)i * NN + j], 0);
                else
                    Kv = outb[idx];
                bool c = (fabsf(ys[r] - yj) <= 0.1f) && (fabsf(xs2[r] - xj) <= 0.1f);
                v = c ? Kv * as_[r] * bj * 4096.0f : 0.0f;
            } else {
                v = E * as_[r] * bj * 4096.0f;
            }
            outb[idx] = v;
        }
    }
}

extern "C" void kernel_launch(void* const* d_in, const int* in_sizes, int n_in,
                              void* d_out, int out_size, void* d_ws, size_t ws_size,
                              hipStream_t stream) {
    const float* F     = (const float*)d_in[0];  // (B, D, N)
    const float* pos   = (const float*)d_in[1];  // (B, N, 2)
    const float* alpha = (const float*)d_in[3];  // (1,)
    float* out = (float*)d_out;
    float* ws  = (float*)d_ws;

    float* avec = ws;
    float* bvec = ws + BN * VSTR;
    float* sums = ws + 2 * BN * VSTR;                 // 41*BN floats
    int*   bar  = (int*)(sums + 41 * BN);             // 8 x 32 ints (per-batch lines)
    unsigned char* K8 = (unsigned char*)(bar + BN * GRP);  // 33.5 MB fp8

    size_t need = (size_t)(2 * BN * VSTR + 41 * BN + BN * GRP) * 4 + (size_t)BN * NN * NN;
    bool fp8 = (ws_size >= need);

    hipLaunchKernelGGL(init_kernel, dim3(64), dim3(256), 0, stream, bvec, BN * VSTR,
                       sums, bar);

    if (fp8) {
        hipLaunchKernelGGL((build_k_kernel<true>), dim3(32, 32, BN), dim3(256), 0, stream,
                           F, out, K8);
        const unsigned char* Kp = K8;
        float* ap = avec; float* bp = bvec; float* sp = sums; int* brp = bar;
        const float* alp = alpha;
        void* params[6] = {(void*)&Kp, (void*)&ap, (void*)&bp, (void*)&sp,
                           (void*)&brp, (void*)&alp};
        hipLaunchCooperativeKernel((const void*)sink_persist, dim3(NBLK), dim3(1024),
                                   params, 0, stream);
        hipLaunchKernelGGL((final_kernel<true>), dim3((NP1 + 15) / 16, BN), dim3(256), 0,
                           stream, out, K8, avec, bvec, pos, alpha);
    } else {
        hipLaunchKernelGGL((build_k_kernel<false>), dim3(32, 32, BN), dim3(256), 0, stream,
                           F, out, K8);
        const float* xin = bvec;
        float* xout = avec;
        for (int p = 1; p <= 2 * NITER; p++) {
            hipLaunchKernelGGL(sink_pass_f32, dim3(NN / 16, BN), dim3(256), 0, stream,
                               out, xin, xout, sums + (p - 1) * BN, sums + p * BN, alpha);
            float* tmp = (float*)xin; xin = xout; xout = tmp;
        }
        hipLaunchKernelGGL((final_kernel<false>), dim3((NP1 + 15) / 16, BN), dim3(256), 0,
                           stream, out, K8, avec, bvec, pos, alpha);
    }
}